// Round 2
// baseline (1607.027 us; speedup 1.0000x reference)
//
#include <hip/hip_runtime.h>
#include <math.h>

#define BB 2
#define NN 512
#define SDIM 384
#define ZDIM 128
#define HH 12
#define CDIM 16
#define PQ 4
#define PV 8
#define BN (BB*NN)        // 1024
#define CATD 2112
#define JB 64             // j-chunk size for fused attention
#define NCH 8             // 512 / JB

#define WL  0.57735026918962576f
#define LAM 0.06804138174397717f   // wL*wC/2, wC = sqrt(2/(9*PQ))

// ---- workspace layout (float offsets) ----
#define OFF_Q    0                         // [1024][192] rows
#define OFF_QP   196608                    // [1024][144] rows
#define OFF_QQ   344064                    // [1024][12]
#define OFF_KT4  356352                    // f4: [2][48][512]  (c4-group major, n minor)
#define OFF_KPT4 552960                    // f4: [2][36][512]
#define OFF_KKT  700416                    // [2][12][512]
#define OFF_V    712704                    // [1024][192] rows (f4 view [1024][48])
#define OFF_VP   909312                    // [1024][288] rows (f4 view [1024][72])
#define OFF_CAT  7495680                   // [1024][2112]

__device__ __forceinline__ float dot4(float4 a, float4 b) {
    return a.x*b.x + a.y*b.y + a.z*b.z + a.w*b.w;
}
__device__ __forceinline__ void fma4(float4& a, float s, float4 b) {
    a.x += s*b.x; a.y += s*b.y; a.z += s*b.z; a.w += s*b.w;
}
__device__ __forceinline__ void add4(float4& a, float4 b) {
    a.x += b.x; a.y += b.y; a.z += b.z; a.w += b.w;
}
__device__ __forceinline__ void mul4(float4& a, float s) {
    a.x *= s; a.y *= s; a.z *= s; a.w *= s;
}

// ---------------- Kernel 1: tiled projections + frame transform -------------
// Grid 384 = 16 row-tiles (64 rows) x 24 col-tiles (48 cols). 128 threads.
// Thread owns 2 rows (rr, rr+32) x 12 cols (3 float4 accs each).
// s read per-row float4 (L1/L2); W read as L1-broadcast float4 (4 clusters/wave).
// Weight traffic: 16 row-tiles x 1.7MB = 28MB (was 676MB).
__global__ __launch_bounds__(128) void k_proj(
    const float* __restrict__ s, const float* __restrict__ Rg, const float* __restrict__ tg,
    const float* __restrict__ Wq, const float* __restrict__ Wk, const float* __restrict__ Wv,
    const float* __restrict__ Wqp, const float* __restrict__ Wkp, const float* __restrict__ Wvp,
    float* __restrict__ ws)
{
    const int x = blockIdx.x;
    const int ct = x % 24, rt = x / 24;
    const int t  = threadIdx.x;
    const int rr = t >> 2;        // 0..31
    const int cg = t & 3;         // 0..3 -> cols cg*12..cg*12+11 within 48-col tile
    const int bnA = rt*64 + rr;
    const int bnB = bnA + 32;

    const float4* Wsel; int ld4, cb4, reg;
    if (ct < 4)       { Wsel=(const float4*)Wq;  ld4=48; cb4=ct*12;      reg=0; }
    else if (ct < 8)  { Wsel=(const float4*)Wk;  ld4=48; cb4=(ct-4)*12;  reg=1; }
    else if (ct < 12) { Wsel=(const float4*)Wv;  ld4=48; cb4=(ct-8)*12;  reg=2; }
    else if (ct < 15) { Wsel=(const float4*)Wqp; ld4=36; cb4=(ct-12)*12; reg=3; }
    else if (ct < 18) { Wsel=(const float4*)Wkp; ld4=36; cb4=(ct-15)*12; reg=4; }
    else              { Wsel=(const float4*)Wvp; ld4=72; cb4=(ct-18)*12; reg=5; }
    const float4* Wp = Wsel + cb4 + cg*3;

    const float4* sA4 = (const float4*)s + (size_t)bnA*96;
    const float4* sB4 = (const float4*)s + (size_t)bnB*96;

    float4 a0={0,0,0,0}, a1={0,0,0,0}, a2={0,0,0,0};
    float4 b0={0,0,0,0}, b1={0,0,0,0}, b2={0,0,0,0};

    #pragma unroll 2
    for (int k4 = 0; k4 < 96; ++k4) {
        const float4 sA = sA4[k4];
        const float4 sB = sB4[k4];
        #pragma unroll
        for (int kk = 0; kk < 4; ++kk) {
            const float4* wrow = Wp + (size_t)(k4*4 + kk)*ld4;
            const float4 w0 = wrow[0];
            const float4 w1 = wrow[1];
            const float4 w2 = wrow[2];
            const float fA = ((const float*)&sA)[kk];
            const float fB = ((const float*)&sB)[kk];
            fma4(a0,fA,w0); fma4(a1,fA,w1); fma4(a2,fA,w2);
            fma4(b0,fB,w0); fma4(b1,fB,w1); fma4(b2,fB,w2);
        }
    }

    // ---- epilogue: layout scatter + frame transform, per owned row ----
    #pragma unroll
    for (int half = 0; half < 2; ++half) {
        const int bn = half ? bnB : bnA;
        const float4 c0 = half ? b0 : a0;
        const float4 c1 = half ? b1 : a1;
        const float4 c2 = half ? b2 : a2;
        const int b = bn >> 9, nloc = bn & 511;
        if (reg == 0) {
            const int c4 = ct*12 + cg*3;
            float4* d = (float4*)(ws + OFF_Q) + (size_t)bn*48 + c4;
            d[0]=c0; d[1]=c1; d[2]=c2;
        } else if (reg == 1) {
            const int c4 = (ct-4)*12 + cg*3;
            float4* KT4g = (float4*)(ws + OFF_KT4);
            KT4g[((size_t)(b*48 + c4+0))*512 + nloc] = c0;
            KT4g[((size_t)(b*48 + c4+1))*512 + nloc] = c1;
            KT4g[((size_t)(b*48 + c4+2))*512 + nloc] = c2;
        } else if (reg == 2) {
            const int c4 = (ct-8)*12 + cg*3;
            float4* d = (float4*)(ws + OFF_V) + (size_t)bn*48 + c4;
            d[0]=c0; d[1]=c1; d[2]=c2;
        } else {
            const float* Rp = Rg + (size_t)bn*9;
            const float* tp = tg + (size_t)bn*3;
            const float R0=Rp[0],R1=Rp[1],R2=Rp[2],R3=Rp[3],R4=Rp[4];
            const float R5=Rp[5],R6=Rp[6],R7=Rp[7],R8=Rp[8];
            const float t0=tp[0],t1=tp[1],t2=tp[2];
            const float pl[12] = {c0.x,c0.y,c0.z,c0.w,c1.x,c1.y,c1.z,c1.w,
                                  c2.x,c2.y,c2.z,c2.w};
            float gl[12]; float sq = 0.f;
            #pragma unroll
            for (int p = 0; p < 4; ++p) {
                const float p0 = pl[p*3], p1 = pl[p*3+1], p2 = pl[p*3+2];
                const float g0 = R0*p0 + R1*p1 + R2*p2 + t0;
                const float g1 = R3*p0 + R4*p1 + R5*p2 + t1;
                const float g2 = R6*p0 + R7*p1 + R8*p2 + t2;
                gl[p*3]=g0; gl[p*3+1]=g1; gl[p*3+2]=g2;
                sq += g0*g0 + g1*g1 + g2*g2;
            }
            if (reg == 3) {
                const int cl = (ct-12)*48 + cg*12;     // 0..143, mult of 12
                const int h = cl/12;
                float* d = ws + OFF_QP + (size_t)bn*144 + cl;
                ((float4*)d)[0] = make_float4(gl[0],gl[1],gl[2],gl[3]);
                ((float4*)d)[1] = make_float4(gl[4],gl[5],gl[6],gl[7]);
                ((float4*)d)[2] = make_float4(gl[8],gl[9],gl[10],gl[11]);
                ws[OFF_QQ + (size_t)bn*12 + h] = sq;
            } else if (reg == 4) {
                const int cl = (ct-15)*48 + cg*12;
                const int h = cl/12;
                #pragma unroll
                for (int xx = 0; xx < 12; ++xx) {
                    const int pcx = cl + xx;
                    ws[OFF_KPT4 + (((size_t)(b*36 + (pcx>>2)))*512 + nloc)*4 + (pcx&3)] = gl[xx];
                }
                ws[OFF_KKT + ((size_t)(b*12 + h))*512 + nloc] = sq;
            } else {
                const int cl = (ct-18)*48 + cg*12;     // 0..287
                float* d = ws + OFF_VP + (size_t)bn*288 + cl;
                ((float4*)d)[0] = make_float4(gl[0],gl[1],gl[2],gl[3]);
                ((float4*)d)[1] = make_float4(gl[4],gl[5],gl[6],gl[7]);
                ((float4*)d)[2] = make_float4(gl[8],gl[9],gl[10],gl[11]);
            }
        }
    }
}

// ---------------- Kernel 2: fused bias + flash attention per (b,i) ----------
// JB=64 chunks: z staged once (coalesced), bias from LDS, online softmax.
// LDS 38.4KB -> 4 blocks/CU (32 waves). No register prefetch (no spills).
__global__ __launch_bounds__(512, 4) void k_attn(
    const float* __restrict__ z, const float* __restrict__ Rg, const float* __restrict__ tg,
    const float* __restrict__ hw, const float* __restrict__ Wb, float* __restrict__ ws)
{
    // smem (floats): zs [64][132] : 0..8448 | aL [12][68] : 8448..9264
    //                optg 288 : 9264..9552 | mrun/lrun/fLs 12x3 : 9552..9588
    //                RiL 9 | tiL 3 : 9588..9600   -> 38400 B total
    __shared__ __align__(16) float smem[9600];
    float* zs   = smem;
    float* aL   = smem + 8448;
    float* optg = smem + 9264;
    float* mrun = smem + 9552;
    float* lrun = smem + 9564;
    float* fLs  = smem + 9576;
    float* RiL  = smem + 9588;
    float* tiL  = smem + 9597;

    const int t = threadIdx.x;
    // batch-aware XCD swizzle: XCDs 0..3 get batch 0, 4..7 batch 1 (perf only)
    const int d = blockIdx.x;
    const int xcd = d & 7, slot = d >> 3;
    const int bi = (xcd < 4) ? (xcd*128 + slot) : (512 + (xcd-4)*128 + slot);
    const int b  = bi >> 9;

    if (t < 9)             RiL[t]   = Rg[bi*9 + t];
    if (t >= 9 && t < 12)  tiL[t-9] = tg[bi*3 + (t-9)];
    if (t >= 16 && t < 28) { mrun[t-16] = -1e30f; lrun[t-16] = 0.f; }

    const int jj = t >> 3;     // chunk-local j (0..63)
    const int oc = t & 7;      // z-channel 16-slice + head role

    // softplus(head_weights) for this thread's heads: h1=oc, h2=oc+8 (oc<4)
    const float hx1 = hw[oc];
    const float gam1 = (hx1 > 20.f) ? hx1 : log1pf(__expf(hx1));
    const int  h2i = (oc < 4) ? oc + 8 : oc;
    const float hx2 = hw[h2i];
    const float gam2 = (hx2 > 20.f) ? hx2 : log1pf(__expf(hx2));

    // phase-C roles (3 j-segments x 168 slot-threads)
    int seg = 0, u = 0, typ = 3, hg = 0, zc4 = 0, c4 = 0, po = 0;
    if (t < 504) {
        seg = (t >= 336) ? 2 : (t >= 168) ? 1 : 0;
        u = t - seg*168;
        if (u < 128)      { typ = 0; hg = u >> 5; zc4 = u & 31; }
        else if (u < 144) { typ = 1; hg = (u-128) >> 2; c4 = (u-128) & 3; }
        else              { typ = 2; hg = (u-144) / 6;  po = (u-144) % 6; }
    }
    const int sj0 = seg*20;
    const int sj1 = (seg == 2) ? JB : sj0 + 20;

    const float4* zg4 = (const float4*)z + (size_t)bi*NN*32;
    float4* zs4 = (float4*)zs;

    // stage chunk 0 (coalesced; padded rows, stride 33 f4)
    #pragma unroll
    for (int k2 = 0; k2 < 4; ++k2) {
        const int i = t + 512*k2;
        zs4[(i>>5)*33 + (i&31)] = zg4[i];
    }

    const float4* Q4u  = (const float4*)(ws + OFF_Q  + (size_t)bi*192);
    const float4* QP4u = (const float4*)(ws + OFF_QP + (size_t)bi*144);
    const float*  QQu  = ws + OFF_QQ + (size_t)bi*12;
    const float4* KT4  = (const float4*)(ws + OFF_KT4)  + (size_t)b*48*512;
    const float4* KPT4 = (const float4*)(ws + OFF_KPT4) + (size_t)b*36*512;
    const float*  KKT  = ws + OFF_KKT  + (size_t)b*12*512;

    float4 acc0 = {0,0,0,0}, acc1 = {0,0,0,0}, acc2 = {0,0,0,0};

    for (int ch = 0; ch < NCH; ++ch) {
        const int j0 = ch*JB;
        __syncthreads();                    // zs staged; aL free

        // ---- phase A: pair bias (z from LDS, Wb from L1) + logits ----
        {
            float pb[12];
            #pragma unroll
            for (int h = 0; h < 12; ++h) pb[h] = 0.f;
            #pragma unroll
            for (int c = 0; c < 4; ++c) {
                const float4 zq = zs4[jj*33 + oc*4 + c];
                const float* wr = Wb + (oc*16 + c*4)*12;
                #pragma unroll
                for (int w = 0; w < 4; ++w) {
                    const float zv = ((const float*)&zq)[w];
                    const float4 w0 = *(const float4*)(wr + w*12);
                    const float4 w1 = *(const float4*)(wr + w*12 + 4);
                    const float4 w2 = *(const float4*)(wr + w*12 + 8);
                    pb[0] += zv*w0.x; pb[1] += zv*w0.y; pb[2]  += zv*w0.z; pb[3]  += zv*w0.w;
                    pb[4] += zv*w1.x; pb[5] += zv*w1.y; pb[6]  += zv*w1.z; pb[7]  += zv*w1.w;
                    pb[8] += zv*w2.x; pb[9] += zv*w2.y; pb[10] += zv*w2.z; pb[11] += zv*w2.w;
                }
            }
            #pragma unroll
            for (int h = 0; h < 12; ++h) {      // reduce 8 channel-slices per j
                pb[h] += __shfl_xor(pb[h], 1);
                pb[h] += __shfl_xor(pb[h], 2);
                pb[h] += __shfl_xor(pb[h], 4);
            }
            const int jg = j0 + jj;
            {
                const int h = oc;
                float scal = 0.f, qk = 0.f;
                #pragma unroll
                for (int cg2 = 0; cg2 < 4; ++cg2)
                    scal += dot4(Q4u[h*4+cg2], KT4[(size_t)(h*4+cg2)*512 + jg]);
                #pragma unroll
                for (int pg = 0; pg < 3; ++pg)
                    qk += dot4(QP4u[h*3+pg], KPT4[(size_t)(h*3+pg)*512 + jg]);
                const float dist2 = QQu[h] + KKT[h*512 + jg] - 2.f*qk;
                aL[h*68 + jj] = WL*(scal*0.25f + pb[h]) - LAM*gam1*dist2;
            }
            if (oc < 4) {
                const int h = oc + 8;
                float scal = 0.f, qk = 0.f;
                #pragma unroll
                for (int cg2 = 0; cg2 < 4; ++cg2)
                    scal += dot4(Q4u[h*4+cg2], KT4[(size_t)(h*4+cg2)*512 + jg]);
                #pragma unroll
                for (int pg = 0; pg < 3; ++pg)
                    qk += dot4(QP4u[h*3+pg], KPT4[(size_t)(h*3+pg)*512 + jg]);
                const float dist2 = QQu[h] + KKT[h*512 + jg] - 2.f*qk;
                aL[h*68 + jj] = WL*(scal*0.25f + pb[h]) - LAM*gam2*dist2;
            }
        }
        __syncthreads();

        // ---- phase B: online softmax (wave per head; rows of 64) ----
        {
            const int w = t >> 6, lane = t & 63;
            #pragma unroll
            for (int rep = 0; rep < 2; ++rep) {
                const int h = w + rep*8;
                if (h < 12) {
                    float* row = aL + h*68;
                    const float v = row[lane];
                    float mx = v;
                    #pragma unroll
                    for (int off = 32; off > 0; off >>= 1) mx = fmaxf(mx, __shfl_xor(mx, off));
                    const float mo = mrun[h];
                    const float mn = fmaxf(mo, mx);
                    const float e = __expf(v - mn);
                    float ssum = e;
                    #pragma unroll
                    for (int off = 32; off > 0; off >>= 1) ssum += __shfl_xor(ssum, off);
                    row[lane] = e;
                    if (lane == 0) {
                        const float f = __expf(mo - mn);   // chunk 0: 0
                        fLs[h]  = f;
                        mrun[h] = mn;
                        lrun[h] = lrun[h]*f + ssum;
                    }
                }
            }
        }
        __syncthreads();

        // ---- phase C: rescale + accumulate opair/o/opt_g ----
        if (t < 504) {
            const float f0 = fLs[hg], f1 = fLs[hg+4], f2 = fLs[hg+8];
            mul4(acc0, f0); mul4(acc1, f1); mul4(acc2, f2);
            const float* a0p = aL + hg*68;
            const float* a1p = aL + (hg+4)*68;
            const float* a2p = aL + (hg+8)*68;
            if (typ == 0) {
                for (int jt = sj0; jt < sj1; jt += 4) {
                    float4 av0 = *(const float4*)(a0p + jt);
                    float4 av1 = *(const float4*)(a1p + jt);
                    float4 av2 = *(const float4*)(a2p + jt);
                    #pragma unroll
                    for (int e = 0; e < 4; ++e) {
                        const float4 zq = zs4[(jt+e)*33 + zc4];
                        fma4(acc0, ((const float*)&av0)[e], zq);
                        fma4(acc1, ((const float*)&av1)[e], zq);
                        fma4(acc2, ((const float*)&av2)[e], zq);
                    }
                }
            } else if (typ == 1) {
                const float4* Vp = (const float4*)(ws + OFF_V) + (size_t)b*512*48;
                for (int jt = sj0; jt < sj1; jt += 4) {
                    float4 av0 = *(const float4*)(a0p + jt);
                    float4 av1 = *(const float4*)(a1p + jt);
                    float4 av2 = *(const float4*)(a2p + jt);
                    #pragma unroll
                    for (int e = 0; e < 4; ++e) {
                        const size_t jb = (size_t)(j0 + jt + e)*48;
                        fma4(acc0, ((const float*)&av0)[e], Vp[jb + (hg  )*4 + c4]);
                        fma4(acc1, ((const float*)&av1)[e], Vp[jb + (hg+4)*4 + c4]);
                        fma4(acc2, ((const float*)&av2)[e], Vp[jb + (hg+8)*4 + c4]);
                    }
                }
            } else {
                const float4* VPp = (const float4*)(ws + OFF_VP) + (size_t)b*512*72;
                for (int jt = sj0; jt < sj1; jt += 4) {
                    float4 av0 = *(const float4*)(a0p + jt);
                    float4 av1 = *(const float4*)(a1p + jt);
                    float4 av2 = *(const float4*)(a2p + jt);
                    #pragma unroll
                    for (int e = 0; e < 4; ++e) {
                        const size_t jb = (size_t)(j0 + jt + e)*72;
                        fma4(acc0, ((const float*)&av0)[e], VPp[jb + (hg  )*6 + po]);
                        fma4(acc1, ((const float*)&av1)[e], VPp[jb + (hg+4)*6 + po]);
                        fma4(acc2, ((const float*)&av2)[e], VPp[jb + (hg+8)*6 + po]);
                    }
                }
            }
        }
        __syncthreads();                    // zs/aL consumed
        if (ch < NCH-1) {                   // stage next chunk (coalesced)
            const float4* src = zg4 + (size_t)(j0 + JB)*32;
            #pragma unroll
            for (int k2 = 0; k2 < 4; ++k2) {
                const int i = t + 512*k2;
                zs4[(i>>5)*33 + (i&31)] = src[i];
            }
        }
    }
    __syncthreads();

    // ---- cross-segment reduction (scratch aliases zs), normalize by l ----
    float4* sc4 = (float4*)zs;
    if (t < 504 && seg > 0) {
        const int si = ((seg-1)*168 + u)*3;
        sc4[si] = acc0; sc4[si+1] = acc1; sc4[si+2] = acc2;
    }
    __syncthreads();

    float4* optg4 = (float4*)optg;
    if (t < 168) {
        #pragma unroll
        for (int ssg = 0; ssg < 2; ++ssg) {
            const int si = (ssg*168 + t)*3;
            add4(acc0, sc4[si]); add4(acc1, sc4[si+1]); add4(acc2, sc4[si+2]);
        }
        const float iv0 = 1.f/lrun[hg];
        const float iv1 = 1.f/lrun[hg+4];
        const float iv2 = 1.f/lrun[hg+8];
        mul4(acc0, iv0); mul4(acc1, iv1); mul4(acc2, iv2);
        float4* cat4 = (float4*)(ws + OFF_CAT);
        const size_t cb = (size_t)bi * 528;          // 2112/4
        if (typ == 0) {
            cat4[cb + 144 + (hg  )*32 + zc4] = acc0;
            cat4[cb + 144 + (hg+4)*32 + zc4] = acc1;
            cat4[cb + 144 + (hg+8)*32 + zc4] = acc2;
        } else if (typ == 1) {
            cat4[cb + (hg  )*4 + c4] = acc0;
            cat4[cb + (hg+4)*4 + c4] = acc1;
            cat4[cb + (hg+8)*4 + c4] = acc2;
        } else {
            optg4[(hg  )*6 + po] = acc0;
            optg4[(hg+4)*6 + po] = acc1;
            optg4[(hg+8)*6 + po] = acc2;
        }
    }
    __syncthreads();

    if (t < 96) {
        const float* og = optg;
        const int h = t >> 3, p = t & 7;
        const int o = h*24 + p*3;
        const float d0 = og[o]   - tiL[0];
        const float d1 = og[o+1] - tiL[1];
        const float d2 = og[o+2] - tiL[2];
        const float ox = RiL[0]*d0 + RiL[3]*d1 + RiL[6]*d2;
        const float oy = RiL[1]*d0 + RiL[4]*d1 + RiL[7]*d2;
        const float oz = RiL[2]*d0 + RiL[5]*d1 + RiL[8]*d2;
        float* cat = ws + OFF_CAT + (size_t)bi*CATD;
        cat[192 + o]     = ox;
        cat[192 + o + 1] = oy;
        cat[192 + o + 2] = oz;
        cat[480 + h*8 + p] = sqrtf(ox*ox + oy*oy + oz*oz + 1e-8f);
    }
}

// ---------------- Kernel 3: out = cat @ Wout (cat via scalar loads) ---------
__global__ __launch_bounds__(384) void k_out(
    const float* __restrict__ Wout, const float* __restrict__ ws, float* __restrict__ out)
{
    const int t = threadIdx.x;                 // col 0..383
    const int row0 = blockIdx.x * 4;
    const float* c0 = ws + OFF_CAT + (size_t)(row0+0)*CATD;
    const float* c1 = c0 + CATD;
    const float* c2 = c1 + CATD;
    const float* c3 = c2 + CATD;
    float a0 = 0.f, a1 = 0.f, a2 = 0.f, a3 = 0.f;
    #pragma unroll 8
    for (int r = 0; r < CATD; ++r) {
        float w = Wout[(size_t)r*384 + t];
        a0 += c0[r]*w; a1 += c1[r]*w; a2 += c2[r]*w; a3 += c3[r]*w;
    }
    out[(size_t)(row0+0)*384 + t] = a0;
    out[(size_t)(row0+1)*384 + t] = a1;
    out[(size_t)(row0+2)*384 + t] = a2;
    out[(size_t)(row0+3)*384 + t] = a3;
}

extern "C" void kernel_launch(void* const* d_in, const int* in_sizes, int n_in,
                              void* d_out, int out_size, void* d_ws, size_t ws_size,
                              hipStream_t stream)
{
    const float* s    = (const float*)d_in[0];
    const float* z    = (const float*)d_in[1];
    const float* R    = (const float*)d_in[2];
    const float* tt   = (const float*)d_in[3];
    const float* Wq   = (const float*)d_in[4];
    const float* Wk   = (const float*)d_in[5];
    const float* Wv   = (const float*)d_in[6];
    const float* Wqp  = (const float*)d_in[7];
    const float* Wkp  = (const float*)d_in[8];
    const float* Wvp  = (const float*)d_in[9];
    const float* Wb   = (const float*)d_in[10];
    const float* hw   = (const float*)d_in[11];
    const float* Wout = (const float*)d_in[12];
    float* ws  = (float*)d_ws;
    float* out = (float*)d_out;

    hipLaunchKernelGGL(k_proj, dim3(384),  dim3(128), 0, stream,
                       s, R, tt, Wq, Wk, Wv, Wqp, Wkp, Wvp, ws);
    hipLaunchKernelGGL(k_attn, dim3(BN),   dim3(512), 0, stream, z, R, tt, hw, Wb, ws);
    hipLaunchKernelGGL(k_out,  dim3(BN/4), dim3(384), 0, stream, Wout, ws, out);
}

// Round 3
// 885.896 us; speedup vs baseline: 1.8140x; 1.8140x over previous
//
#include <hip/hip_runtime.h>
#include <math.h>

#define BB 2
#define NN 512
#define SDIM 384
#define ZDIM 128
#define HH 12
#define CDIM 16
#define PQ 4
#define PV 8
#define BN (BB*NN)        // 1024
#define CATD 2112

#define WL  0.57735026918962576f
#define LAM 0.06804138174397717f   // wL*wC/2, wC = sqrt(2/(9*PQ))

// ---- workspace layout (float offsets) ----
#define OFF_Q    0                         // [1024][192] rows
#define OFF_QP   196608                    // [1024][144] rows
#define OFF_QQ   344064                    // [1024][12]
#define OFF_KT4  356352                    // f4: [2][48][512]  (c4-group major, n minor)
#define OFF_KPT4 552960                    // f4: [2][36][512]
#define OFF_KKT  700416                    // [2][12][512]
#define OFF_V    712704                    // [1024][192] rows (f4 view [1024][48])
#define OFF_VP   909312                    // [1024][288] rows (f4 view [1024][72])
#define OFF_BIAS 1204224                   // [2][512 i][12 h][512 j]
#define OFF_CAT  7495680                   // [1024][2112]

__device__ __forceinline__ float dot4(float4 a, float4 b) {
    return a.x*b.x + a.y*b.y + a.z*b.z + a.w*b.w;
}
__device__ __forceinline__ void fma4(float4& a, float s, float4 b) {
    a.x += s*b.x; a.y += s*b.y; a.z += s*b.z; a.w += s*b.w;
}
__device__ __forceinline__ void add4(float4& a, float4 b) {
    a.x += b.x; a.y += b.y; a.z += b.z; a.w += b.w;
}

// ---------------- Kernel 1: projections + frame transform -------------------
// 2 rows per block, 512 blocks. s rows read via scalar loads (uniform).
__global__ __launch_bounds__(256) void k_proj(
    const float* __restrict__ s, const float* __restrict__ Rg, const float* __restrict__ tg,
    const float* __restrict__ Wq, const float* __restrict__ Wk, const float* __restrict__ Wv,
    const float* __restrict__ Wqp, const float* __restrict__ Wkp, const float* __restrict__ Wvp,
    float* __restrict__ ws)
{
    __shared__ float4 pL4[2][144];   // point projections (local frame), rows 0/1
    __shared__ float  sqL[2][96];    // |qp|^2 [0:48), |kp|^2 [48:96)
    __shared__ float  Rt[2][12];
    const int t = threadIdx.x;
    const int n0 = blockIdx.x * 2;
    const int b  = n0 >> 9;
    const int nloc = n0 & 511;

    if (t < 24) {
        int rr = t / 12, c = t % 12;
        Rt[rr][c] = (c < 9) ? Rg[(n0+rr)*9 + c] : tg[(n0+rr)*3 + (c-9)];
    }
    const float* s0 = s + (size_t)n0*SDIM;
    const float* s1 = s0 + SDIM;
    __syncthreads();

    float4* Q4g  = (float4*)(ws + OFF_Q);
    float4* V4g  = (float4*)(ws + OFF_V);
    float4* KT4g = (float4*)(ws + OFF_KT4);

    for (int it = 0; it < 2; ++it) {
        int g = t + it*256;
        if (g >= 288) break;
        const float4* W4; int wc4, ld4, dst;
        if (g < 48)       { W4 = (const float4*)Wq;  wc4 = g;     ld4 = 48; dst = 0; }
        else if (g < 96)  { W4 = (const float4*)Wk;  wc4 = g-48;  ld4 = 48; dst = 1; }
        else if (g < 144) { W4 = (const float4*)Wv;  wc4 = g-96;  ld4 = 48; dst = 2; }
        else if (g < 180) { W4 = (const float4*)Wqp; wc4 = g-144; ld4 = 36; dst = 3; }
        else if (g < 216) { W4 = (const float4*)Wkp; wc4 = g-180; ld4 = 36; dst = 4; }
        else              { W4 = (const float4*)Wvp; wc4 = g-216; ld4 = 72; dst = 5; }
        float4 acc0 = {0,0,0,0}, acc1 = {0,0,0,0};
        #pragma unroll 4
        for (int r = 0; r < SDIM; ++r) {
            float4 wv = W4[r*ld4 + wc4];
            float f0 = s0[r], f1 = s1[r];
            fma4(acc0, f0, wv);
            fma4(acc1, f1, wv);
        }
        if (dst == 0) {
            Q4g[(size_t)n0*48 + wc4] = acc0;
            Q4g[(size_t)(n0+1)*48 + wc4] = acc1;
        } else if (dst == 1) {
            size_t base = ((size_t)(b*48 + wc4))*512 + nloc;
            KT4g[base] = acc0; KT4g[base+1] = acc1;
        } else if (dst == 2) {
            V4g[(size_t)n0*48 + wc4] = acc0;
            V4g[(size_t)(n0+1)*48 + wc4] = acc1;
        } else if (dst == 3) {
            pL4[0][wc4] = acc0; pL4[1][wc4] = acc1;
        } else if (dst == 4) {
            pL4[0][36+wc4] = acc0; pL4[1][36+wc4] = acc1;
        } else {
            pL4[0][72+wc4] = acc0; pL4[1][72+wc4] = acc1;
        }
    }
    __syncthreads();

    // local -> global frame
    for (int task = t; task < 384; task += 256) {
        int rr = task / 192, pt = task % 192;
        const float* pl = (const float*)pL4[rr];
        int off = (pt < 48) ? pt*3 : (pt < 96 ? 144 + (pt-48)*3 : 288 + (pt-96)*3);
        float p0 = pl[off], p1 = pl[off+1], p2 = pl[off+2];
        const float* R = Rt[rr];
        float g0 = R[0]*p0 + R[1]*p1 + R[2]*p2 + R[9];
        float g1 = R[3]*p0 + R[4]*p1 + R[5]*p2 + R[10];
        float g2 = R[6]*p0 + R[7]*p1 + R[8]*p2 + R[11];
        int bn = n0 + rr, n = bn & 511;
        if (pt < 48) {
            int o = pt*3;
            float* d = ws + OFF_QP + (size_t)bn*144 + o;
            d[0] = g0; d[1] = g1; d[2] = g2;
            sqL[rr][pt] = g0*g0 + g1*g1 + g2*g2;
        } else if (pt < 96) {
            int pc = (pt-48)*3;
            float gg[3] = {g0,g1,g2};
            #pragma unroll
            for (int x = 0; x < 3; ++x) {
                int pcx = pc + x;
                ws[OFF_KPT4 + (((size_t)(b*36 + (pcx>>2)))*512 + n)*4 + (pcx&3)] = gg[x];
            }
            sqL[rr][pt] = g0*g0 + g1*g1 + g2*g2;
        } else {
            int o = (pt-96)*3;
            float* d = ws + OFF_VP + (size_t)bn*288 + o;
            d[0] = g0; d[1] = g1; d[2] = g2;
        }
    }
    __syncthreads();

    if (t < 48) {
        int rr = t / 24, u = t % 24;
        int bn = n0 + rr, n = bn & 511;
        if (u < 12) {
            float sm = sqL[rr][u*4] + sqL[rr][u*4+1] + sqL[rr][u*4+2] + sqL[rr][u*4+3];
            ws[OFF_QQ + (size_t)bn*12 + u] = sm;
        } else {
            int h = u - 12;
            float sm = sqL[rr][48+h*4] + sqL[rr][48+h*4+1] + sqL[rr][48+h*4+2] + sqL[rr][48+h*4+3];
            ws[OFF_KKT + ((size_t)(b*12 + h))*512 + n] = sm;
        }
    }
}

// ---------------- Kernel 2: pair bias (Wb via scalar loads) -----------------
__global__ __launch_bounds__(256) void k_bias(
    const float* __restrict__ z, const float* __restrict__ Wb, float* __restrict__ ws)
{
    const int t = threadIdx.x;
    const int p = blockIdx.x*256 + t;          // (b,i,j) flat
    const float4* z4 = (const float4*)z + (size_t)p*32;
    float acc[HH];
    #pragma unroll
    for (int h = 0; h < HH; ++h) acc[h] = 0.f;
    #pragma unroll 8
    for (int q = 0; q < 32; ++q) {
        float4 zq = z4[q];
        const float* wb = Wb + q*48;           // uniform -> s_load
        #pragma unroll
        for (int h = 0; h < HH; ++h)
            acc[h] += zq.x*wb[h] + zq.y*wb[12+h] + zq.z*wb[24+h] + zq.w*wb[36+h];
    }
    const int bi = p >> 9, j = p & 511;
    float* BI = ws + OFF_BIAS + (size_t)bi*HH*512;
    #pragma unroll
    for (int h = 0; h < HH; ++h)
        BI[h*512 + j] = acc[h];                // coalesced (lanes = consecutive j)
}

// ---------------- Kernel 3: fused attention per (b,i) -----------------------
// launch_bounds (512,2): 2 blocks/CU -> VGPR cap 128 (no spills at ~90 demand).
__global__ __launch_bounds__(512, 2) void k_attn(
    const float* __restrict__ z, const float* __restrict__ Rg, const float* __restrict__ tg,
    const float* __restrict__ hw, float* __restrict__ ws)
{
    __shared__ __align__(16) float aL[HH*516];   // logits -> attention, stride 516
    __shared__ float4 optgS4[72];
    __shared__ float RiL[9], tiL[3];

    const int t = threadIdx.x;
    // batch-aware XCD swizzle: XCDs 0..3 get batch 0, 4..7 batch 1 (perf only)
    const int d = blockIdx.x;
    const int xcd = d & 7, slot = d >> 3;
    const int bi = (xcd < 4) ? (xcd*128 + slot) : (512 + (xcd-4)*128 + slot);
    const int b = bi >> 9;

    if (t < 9)             RiL[t]   = Rg[bi*9 + t];
    if (t >= 9 && t < 12)  tiL[t-9] = tg[bi*3 + (t-9)];

    // gamma (uniform, per-thread registers)
    float gam[HH];
    #pragma unroll
    for (int h = 0; h < HH; ++h) {
        float x = hw[h];
        gam[h] = (x > 20.f) ? x : log1pf(__expf(x));
    }

    // ---- phase A: logits, thread <-> j ----
    {
        const int j = t;
        const float4* Q4u  = (const float4*)(ws + OFF_Q  + (size_t)bi*192);
        const float4* QP4u = (const float4*)(ws + OFF_QP + (size_t)bi*144);
        const float*  QQu  = ws + OFF_QQ + (size_t)bi*12;
        const float4* KT4  = (const float4*)(ws + OFF_KT4)  + (size_t)b*48*512;
        const float4* KPT4 = (const float4*)(ws + OFF_KPT4) + (size_t)b*36*512;
        const float*  KKT  = ws + OFF_KKT  + (size_t)b*12*512;
        const float*  BI   = ws + OFF_BIAS + (size_t)bi*HH*512;
        for (int h = 0; h < HH; ++h) {
            float scal = 0.f, qk = 0.f;
            #pragma unroll
            for (int cg = 0; cg < 4; ++cg)
                scal += dot4(Q4u[h*4+cg], KT4[(h*4+cg)*512 + j]);
            #pragma unroll
            for (int pg = 0; pg < 3; ++pg)
                qk += dot4(QP4u[h*3+pg], KPT4[(h*3+pg)*512 + j]);
            float dist2 = QQu[h] + KKT[h*512 + j] - 2.f*qk;
            aL[h*516 + j] = WL*(scal*0.25f + BI[h*512 + j]) - LAM*gam[h]*dist2;
        }
    }
    __syncthreads();

    // ---- phase B: softmax per head ----
    {
        const int w = t >> 6, lane = t & 63;
        for (int h = w; h < HH; h += 8) {
            float* row = aL + h*516;
            float m = -1e30f;
            #pragma unroll
            for (int k = 0; k < 8; ++k) m = fmaxf(m, row[lane + 64*k]);
            #pragma unroll
            for (int off = 32; off > 0; off >>= 1) m = fmaxf(m, __shfl_xor(m, off));
            float ssum = 0.f;
            #pragma unroll
            for (int k = 0; k < 8; ++k) {
                float e = __expf(row[lane + 64*k] - m);
                row[lane + 64*k] = e;
                ssum += e;
            }
            #pragma unroll
            for (int off = 32; off > 0; off >>= 1) ssum += __shfl_xor(ssum, off);
            float inv = 1.f / ssum;
            #pragma unroll
            for (int k = 0; k < 8; ++k) row[lane + 64*k] *= inv;
        }
    }
    __syncthreads();

    // ---- phase C: accumulate opair/o/opt_g; 3 j-segments x 168 slot-threads ----
    float4 acc0 = {0,0,0,0}, acc1 = {0,0,0,0}, acc2 = {0,0,0,0};
    int seg = 0, u = 0, typ = 3, hg = 0;
    if (t < 504) {
        seg = (t >= 336) ? 2 : (t >= 168) ? 1 : 0;
        u = t - seg*168;
        const int j0 = seg*176, j1 = (seg == 2) ? 512 : j0 + 176;
        if (u < 128) {
            typ = 0; hg = u >> 5;
            const int zc4 = u & 31;
            const float4* Zp = (const float4*)z + (size_t)bi*512*32 + zc4;
            const float* a0p = aL + hg*516;
            const float* a1p = aL + (hg+4)*516;
            const float* a2p = aL + (hg+8)*516;
            // 8 z-loads in flight per group: hides ~900cy HBM latency
            for (int jt = j0; jt < j1; jt += 8) {
                float4 zb0 = Zp[(size_t)(jt+0)*32];
                float4 zb1 = Zp[(size_t)(jt+1)*32];
                float4 zb2 = Zp[(size_t)(jt+2)*32];
                float4 zb3 = Zp[(size_t)(jt+3)*32];
                float4 zb4 = Zp[(size_t)(jt+4)*32];
                float4 zb5 = Zp[(size_t)(jt+5)*32];
                float4 zb6 = Zp[(size_t)(jt+6)*32];
                float4 zb7 = Zp[(size_t)(jt+7)*32];
                float4 av0 = *(const float4*)(a0p + jt);
                float4 av1 = *(const float4*)(a1p + jt);
                float4 av2 = *(const float4*)(a2p + jt);
                float4 aw0 = *(const float4*)(a0p + jt + 4);
                float4 aw1 = *(const float4*)(a1p + jt + 4);
                float4 aw2 = *(const float4*)(a2p + jt + 4);
                fma4(acc0, av0.x, zb0); fma4(acc1, av1.x, zb0); fma4(acc2, av2.x, zb0);
                fma4(acc0, av0.y, zb1); fma4(acc1, av1.y, zb1); fma4(acc2, av2.y, zb1);
                fma4(acc0, av0.z, zb2); fma4(acc1, av1.z, zb2); fma4(acc2, av2.z, zb2);
                fma4(acc0, av0.w, zb3); fma4(acc1, av1.w, zb3); fma4(acc2, av2.w, zb3);
                fma4(acc0, aw0.x, zb4); fma4(acc1, aw1.x, zb4); fma4(acc2, aw2.x, zb4);
                fma4(acc0, aw0.y, zb5); fma4(acc1, aw1.y, zb5); fma4(acc2, aw2.y, zb5);
                fma4(acc0, aw0.z, zb6); fma4(acc1, aw1.z, zb6); fma4(acc2, aw2.z, zb6);
                fma4(acc0, aw0.w, zb7); fma4(acc1, aw1.w, zb7); fma4(acc2, aw2.w, zb7);
            }
        } else if (u < 144) {
            typ = 1; const int v0 = u - 128;
            const int c4 = v0 & 3; hg = v0 >> 2;
            const float4* Vp = (const float4*)(ws + OFF_V) + (size_t)b*512*48;
            const float* a0p = aL + hg*516;
            const float* a1p = aL + (hg+4)*516;
            const float* a2p = aL + (hg+8)*516;
            for (int jt = j0; jt < j1; jt += 4) {
                float4 av0 = *(const float4*)(a0p + jt);
                float4 av1 = *(const float4*)(a1p + jt);
                float4 av2 = *(const float4*)(a2p + jt);
                #pragma unroll
                for (int e = 0; e < 4; ++e) {
                    size_t jb = (size_t)(jt+e)*48;
                    fma4(acc0, ((const float*)&av0)[e], Vp[jb + (hg  )*4 + c4]);
                    fma4(acc1, ((const float*)&av1)[e], Vp[jb + (hg+4)*4 + c4]);
                    fma4(acc2, ((const float*)&av2)[e], Vp[jb + (hg+8)*4 + c4]);
                }
            }
        } else {
            typ = 2; const int v0 = u - 144;
            const int po = v0 % 6; hg = v0 / 6;
            const float4* VPp = (const float4*)(ws + OFF_VP) + (size_t)b*512*72;
            const float* a0p = aL + hg*516;
            const float* a1p = aL + (hg+4)*516;
            const float* a2p = aL + (hg+8)*516;
            for (int jt = j0; jt < j1; jt += 4) {
                float4 av0 = *(const float4*)(a0p + jt);
                float4 av1 = *(const float4*)(a1p + jt);
                float4 av2 = *(const float4*)(a2p + jt);
                #pragma unroll
                for (int e = 0; e < 4; ++e) {
                    size_t jb = (size_t)(jt+e)*72;
                    fma4(acc0, ((const float*)&av0)[e], VPp[jb + (hg  )*6 + po]);
                    fma4(acc1, ((const float*)&av1)[e], VPp[jb + (hg+4)*6 + po]);
                    fma4(acc2, ((const float*)&av2)[e], VPp[jb + (hg+8)*6 + po]);
                }
            }
        }
    }
    __syncthreads();                       // all reads of aL done
    float4* sc4 = (float4*)aL;             // reuse aL as reduction scratch
    if (t < 504 && seg > 0) {
        int si = ((seg-1)*168 + u)*3;
        sc4[si] = acc0; sc4[si+1] = acc1; sc4[si+2] = acc2;
    }
    __syncthreads();

    if (t < 168) {
        #pragma unroll
        for (int ss = 0; ss < 2; ++ss) {
            int si = (ss*168 + t)*3;
            add4(acc0, sc4[si]); add4(acc1, sc4[si+1]); add4(acc2, sc4[si+2]);
        }
        float4* cat4 = (float4*)(ws + OFF_CAT);
        const size_t cb = (size_t)bi * 528;          // 2112/4
        if (typ == 0) {
            const int zc4 = u & 31;
            cat4[cb + 144 + (hg  )*32 + zc4] = acc0;
            cat4[cb + 144 + (hg+4)*32 + zc4] = acc1;
            cat4[cb + 144 + (hg+8)*32 + zc4] = acc2;
        } else if (typ == 1) {
            const int c4 = (u-128) & 3;
            cat4[cb + (hg  )*4 + c4] = acc0;
            cat4[cb + (hg+4)*4 + c4] = acc1;
            cat4[cb + (hg+8)*4 + c4] = acc2;
        } else {
            const int po = (u-144) % 6;
            optgS4[(hg  )*6 + po] = acc0;
            optgS4[(hg+4)*6 + po] = acc1;
            optgS4[(hg+8)*6 + po] = acc2;
        }
    }
    __syncthreads();

    if (t < 96) {
        const float* og = (const float*)optgS4;
        int h = t >> 3, p = t & 7;
        int o = h*24 + p*3;
        float d0 = og[o]   - tiL[0];
        float d1 = og[o+1] - tiL[1];
        float d2 = og[o+2] - tiL[2];
        float ox = RiL[0]*d0 + RiL[3]*d1 + RiL[6]*d2;
        float oy = RiL[1]*d0 + RiL[4]*d1 + RiL[7]*d2;
        float oz = RiL[2]*d0 + RiL[5]*d1 + RiL[8]*d2;
        float* cat = ws + OFF_CAT + (size_t)bi*CATD;
        cat[192 + o]     = ox;
        cat[192 + o + 1] = oy;
        cat[192 + o + 2] = oz;
        cat[480 + h*8 + p] = sqrtf(ox*ox + oy*oy + oz*oz + 1e-8f);
    }
}

// ---------------- Kernel 4: out = cat @ Wout (cat via scalar loads) ---------
__global__ __launch_bounds__(384) void k_out(
    const float* __restrict__ Wout, const float* __restrict__ ws, float* __restrict__ out)
{
    const int t = threadIdx.x;                 // col 0..383
    const int row0 = blockIdx.x * 4;
    const float* c0 = ws + OFF_CAT + (size_t)(row0+0)*CATD;
    const float* c1 = c0 + CATD;
    const float* c2 = c1 + CATD;
    const float* c3 = c2 + CATD;
    float a0 = 0.f, a1 = 0.f, a2 = 0.f, a3 = 0.f;
    #pragma unroll 8
    for (int r = 0; r < CATD; ++r) {
        float w = Wout[(size_t)r*384 + t];
        a0 += c0[r]*w; a1 += c1[r]*w; a2 += c2[r]*w; a3 += c3[r]*w;
    }
    out[(size_t)(row0+0)*384 + t] = a0;
    out[(size_t)(row0+1)*384 + t] = a1;
    out[(size_t)(row0+2)*384 + t] = a2;
    out[(size_t)(row0+3)*384 + t] = a3;
}

extern "C" void kernel_launch(void* const* d_in, const int* in_sizes, int n_in,
                              void* d_out, int out_size, void* d_ws, size_t ws_size,
                              hipStream_t stream)
{
    const float* s    = (const float*)d_in[0];
    const float* z    = (const float*)d_in[1];
    const float* R    = (const float*)d_in[2];
    const float* tt   = (const float*)d_in[3];
    const float* Wq   = (const float*)d_in[4];
    const float* Wk   = (const float*)d_in[5];
    const float* Wv   = (const float*)d_in[6];
    const float* Wqp  = (const float*)d_in[7];
    const float* Wkp  = (const float*)d_in[8];
    const float* Wvp  = (const float*)d_in[9];
    const float* Wb   = (const float*)d_in[10];
    const float* hw   = (const float*)d_in[11];
    const float* Wout = (const float*)d_in[12];
    float* ws  = (float*)d_ws;
    float* out = (float*)d_out;

    hipLaunchKernelGGL(k_proj, dim3(BN/2),      dim3(256), 0, stream,
                       s, R, tt, Wq, Wk, Wv, Wqp, Wkp, Wvp, ws);
    hipLaunchKernelGGL(k_bias, dim3(BN*NN/256), dim3(256), 0, stream, z, Wb, ws);
    hipLaunchKernelGGL(k_attn, dim3(BN),        dim3(512), 0, stream, z, R, tt, hw, ws);
    hipLaunchKernelGGL(k_out,  dim3(BN/4),      dim3(384), 0, stream, Wout, ws, out);
}

// Round 4
// 803.324 us; speedup vs baseline: 2.0005x; 1.1028x over previous
//
#include <hip/hip_runtime.h>
#include <math.h>

#define BB 2
#define NN 512
#define SDIM 384
#define ZDIM 128
#define HH 12
#define CDIM 16
#define PQ 4
#define PV 8
#define BN (BB*NN)        // 1024
#define CATD 2112

#define WL  0.57735026918962576f
#define LAM 0.06804138174397717f   // wL*wC/2, wC = sqrt(2/(9*PQ))

// ---- workspace layout (float offsets) ----
#define OFF_Q    0                         // [1024][192] rows
#define OFF_QP   196608                    // [1024][144] rows
#define OFF_QQ   344064                    // [1024][12]
#define OFF_KT4  356352                    // f4: [2][48][512]  (c4-group major, n minor)
#define OFF_KPT4 552960                    // f4: [2][36][512]
#define OFF_KKT  700416                    // [2][12][512]
#define OFF_V    712704                    // [1024][192] rows (f4 view [1024][48])
#define OFF_VP   909312                    // [1024][288] rows (f4 view [1024][72])
#define OFF_BIAS 1204224                   // [2][512 i][12 h][512 j]
#define OFF_CAT  7495680                   // [1024][2112]

__device__ __forceinline__ float dot4(float4 a, float4 b) {
    return a.x*b.x + a.y*b.y + a.z*b.z + a.w*b.w;
}
__device__ __forceinline__ void fma4(float4& a, float s, float4 b) {
    a.x += s*b.x; a.y += s*b.y; a.z += s*b.z; a.w += s*b.w;
}
__device__ __forceinline__ void add4(float4& a, float4 b) {
    a.x += b.x; a.y += b.y; a.z += b.z; a.w += b.w;
}
__device__ __forceinline__ void mul4(float4& a, float s) {
    a.x *= s; a.y *= s; a.z *= s; a.w *= s;
}

// ---------------- Kernel 1: projections + frame transform -------------------
// 2 rows per block, 512 blocks. s rows read via scalar loads (uniform).
__global__ __launch_bounds__(256) void k_proj(
    const float* __restrict__ s, const float* __restrict__ Rg, const float* __restrict__ tg,
    const float* __restrict__ Wq, const float* __restrict__ Wk, const float* __restrict__ Wv,
    const float* __restrict__ Wqp, const float* __restrict__ Wkp, const float* __restrict__ Wvp,
    float* __restrict__ ws)
{
    __shared__ float4 pL4[2][144];   // point projections (local frame), rows 0/1
    __shared__ float  sqL[2][96];    // |qp|^2 [0:48), |kp|^2 [48:96)
    __shared__ float  Rt[2][12];
    const int t = threadIdx.x;
    const int n0 = blockIdx.x * 2;
    const int b  = n0 >> 9;
    const int nloc = n0 & 511;

    if (t < 24) {
        int rr = t / 12, c = t % 12;
        Rt[rr][c] = (c < 9) ? Rg[(n0+rr)*9 + c] : tg[(n0+rr)*3 + (c-9)];
    }
    const float* s0 = s + (size_t)n0*SDIM;
    const float* s1 = s0 + SDIM;
    __syncthreads();

    float4* Q4g  = (float4*)(ws + OFF_Q);
    float4* V4g  = (float4*)(ws + OFF_V);
    float4* KT4g = (float4*)(ws + OFF_KT4);

    for (int it = 0; it < 2; ++it) {
        int g = t + it*256;
        if (g >= 288) break;
        const float4* W4; int wc4, ld4, dst;
        if (g < 48)       { W4 = (const float4*)Wq;  wc4 = g;     ld4 = 48; dst = 0; }
        else if (g < 96)  { W4 = (const float4*)Wk;  wc4 = g-48;  ld4 = 48; dst = 1; }
        else if (g < 144) { W4 = (const float4*)Wv;  wc4 = g-96;  ld4 = 48; dst = 2; }
        else if (g < 180) { W4 = (const float4*)Wqp; wc4 = g-144; ld4 = 36; dst = 3; }
        else if (g < 216) { W4 = (const float4*)Wkp; wc4 = g-180; ld4 = 36; dst = 4; }
        else              { W4 = (const float4*)Wvp; wc4 = g-216; ld4 = 72; dst = 5; }
        float4 acc0 = {0,0,0,0}, acc1 = {0,0,0,0};
        #pragma unroll 4
        for (int r = 0; r < SDIM; ++r) {
            float4 wv = W4[r*ld4 + wc4];
            float f0 = s0[r], f1 = s1[r];
            fma4(acc0, f0, wv);
            fma4(acc1, f1, wv);
        }
        if (dst == 0) {
            Q4g[(size_t)n0*48 + wc4] = acc0;
            Q4g[(size_t)(n0+1)*48 + wc4] = acc1;
        } else if (dst == 1) {
            size_t base = ((size_t)(b*48 + wc4))*512 + nloc;
            KT4g[base] = acc0; KT4g[base+1] = acc1;
        } else if (dst == 2) {
            V4g[(size_t)n0*48 + wc4] = acc0;
            V4g[(size_t)(n0+1)*48 + wc4] = acc1;
        } else if (dst == 3) {
            pL4[0][wc4] = acc0; pL4[1][wc4] = acc1;
        } else if (dst == 4) {
            pL4[0][36+wc4] = acc0; pL4[1][36+wc4] = acc1;
        } else {
            pL4[0][72+wc4] = acc0; pL4[1][72+wc4] = acc1;
        }
    }
    __syncthreads();

    // local -> global frame
    for (int task = t; task < 384; task += 256) {
        int rr = task / 192, pt = task % 192;
        const float* pl = (const float*)pL4[rr];
        int off = (pt < 48) ? pt*3 : (pt < 96 ? 144 + (pt-48)*3 : 288 + (pt-96)*3);
        float p0 = pl[off], p1 = pl[off+1], p2 = pl[off+2];
        const float* R = Rt[rr];
        float g0 = R[0]*p0 + R[1]*p1 + R[2]*p2 + R[9];
        float g1 = R[3]*p0 + R[4]*p1 + R[5]*p2 + R[10];
        float g2 = R[6]*p0 + R[7]*p1 + R[8]*p2 + R[11];
        int bn = n0 + rr, n = bn & 511;
        if (pt < 48) {
            int o = pt*3;
            float* d = ws + OFF_QP + (size_t)bn*144 + o;
            d[0] = g0; d[1] = g1; d[2] = g2;
            sqL[rr][pt] = g0*g0 + g1*g1 + g2*g2;
        } else if (pt < 96) {
            int pc = (pt-48)*3;
            float gg[3] = {g0,g1,g2};
            #pragma unroll
            for (int x = 0; x < 3; ++x) {
                int pcx = pc + x;
                ws[OFF_KPT4 + (((size_t)(b*36 + (pcx>>2)))*512 + n)*4 + (pcx&3)] = gg[x];
            }
            sqL[rr][pt] = g0*g0 + g1*g1 + g2*g2;
        } else {
            int o = (pt-96)*3;
            float* d = ws + OFF_VP + (size_t)bn*288 + o;
            d[0] = g0; d[1] = g1; d[2] = g2;
        }
    }
    __syncthreads();

    if (t < 48) {
        int rr = t / 24, u = t % 24;
        int bn = n0 + rr, n = bn & 511;
        if (u < 12) {
            float sm = sqL[rr][u*4] + sqL[rr][u*4+1] + sqL[rr][u*4+2] + sqL[rr][u*4+3];
            ws[OFF_QQ + (size_t)bn*12 + u] = sm;
        } else {
            int h = u - 12;
            float sm = sqL[rr][48+h*4] + sqL[rr][48+h*4+1] + sqL[rr][48+h*4+2] + sqL[rr][48+h*4+3];
            ws[OFF_KKT + ((size_t)(b*12 + h))*512 + n] = sm;
        }
    }
}

// ---------------- Kernel 2: pair bias, LDS-staged coalesced -----------------
// Block = 64 j-rows of one (b,i). Stage 32KB z coalesced, compute from LDS.
__global__ __launch_bounds__(256) void k_bias(
    const float* __restrict__ z, const float* __restrict__ Wb, float* __restrict__ ws)
{
    __shared__ __align__(16) float4 zsh[64*33];   // row j: zsh[j*33+c4], +1 f4 pad
    const int t = threadIdx.x;
    const int blk = blockIdx.x;                   // 8192
    const int bi = blk >> 3;
    const int j0 = (blk & 7) * 64;
    const float4* zg = (const float4*)z + ((size_t)bi*512 + j0)*32;
    #pragma unroll
    for (int k = 0; k < 8; ++k) {
        const int i = t + 256*k;                  // 0..2047, coalesced
        zsh[(i>>5)*33 + (i&31)] = zg[i];
    }
    __syncthreads();

    const int j  = t >> 2;                        // 0..63
    const int hg = t & 3;                         // heads hg, hg+4, hg+8
    float a0 = 0.f, a1 = 0.f, a2 = 0.f;
    const float4* row = &zsh[j*33];
    #pragma unroll 8
    for (int c4 = 0; c4 < 32; ++c4) {
        const float4 zq = row[c4];
        const float* wb = Wb + c4*48;
        #pragma unroll
        for (int e = 0; e < 4; ++e) {
            const float zv = ((const float*)&zq)[e];
            const float* w = wb + e*12;
            a0 += zv * w[hg];
            a1 += zv * w[hg+4];
            a2 += zv * w[hg+8];
        }
    }
    float* BI = ws + OFF_BIAS + (size_t)bi*HH*512 + j0 + j;
    BI[(hg  )*512] = a0;
    BI[(hg+4)*512] = a1;
    BI[(hg+8)*512] = a2;
}

// ---------------- Kernel 3: fused attention per (b,i) -----------------------
// Phase C: homogeneous waves (0-5 pure z, 6-7 unified V/VP loop) + ping-pong
// register prefetch on the z stream. launch_bounds(512,2): VGPR cap 128.
__global__ __launch_bounds__(512, 2) void k_attn(
    const float* __restrict__ z, const float* __restrict__ Rg, const float* __restrict__ tg,
    const float* __restrict__ hw, float* __restrict__ ws)
{
    __shared__ __align__(16) float aL[HH*516];   // logits/probs; reused as reduce scratch
    __shared__ float4 optgS4[72];
    __shared__ float RiL[9], tiL[3], sInv[12];

    const int t = threadIdx.x;
    // batch-aware XCD swizzle: XCDs 0..3 get batch 0, 4..7 batch 1 (perf only)
    const int d = blockIdx.x;
    const int xcd = d & 7, slot = d >> 3;
    const int bi = (xcd < 4) ? (xcd*128 + slot) : (512 + (xcd-4)*128 + slot);
    const int b = bi >> 9;

    if (t < 9)             RiL[t]   = Rg[bi*9 + t];
    if (t >= 9 && t < 12)  tiL[t-9] = tg[bi*3 + (t-9)];

    // gamma (uniform, per-thread registers)
    float gam[HH];
    #pragma unroll
    for (int h = 0; h < HH; ++h) {
        float x = hw[h];
        gam[h] = (x > 20.f) ? x : log1pf(__expf(x));
    }

    // ---- phase A: logits, thread <-> j ----
    {
        const int j = t;
        const float4* Q4u  = (const float4*)(ws + OFF_Q  + (size_t)bi*192);
        const float4* QP4u = (const float4*)(ws + OFF_QP + (size_t)bi*144);
        const float*  QQu  = ws + OFF_QQ + (size_t)bi*12;
        const float4* KT4  = (const float4*)(ws + OFF_KT4)  + (size_t)b*48*512;
        const float4* KPT4 = (const float4*)(ws + OFF_KPT4) + (size_t)b*36*512;
        const float*  KKT  = ws + OFF_KKT  + (size_t)b*12*512;
        const float*  BI   = ws + OFF_BIAS + (size_t)bi*HH*512;
        for (int h = 0; h < HH; ++h) {
            float scal = 0.f, qk = 0.f;
            #pragma unroll
            for (int cg = 0; cg < 4; ++cg)
                scal += dot4(Q4u[h*4+cg], KT4[(h*4+cg)*512 + j]);
            #pragma unroll
            for (int pg = 0; pg < 3; ++pg)
                qk += dot4(QP4u[h*3+pg], KPT4[(h*3+pg)*512 + j]);
            float dist2 = QQu[h] + KKT[h*512 + j] - 2.f*qk;
            aL[h*516 + j] = WL*(scal*0.25f + BI[h*512 + j]) - LAM*gam[h]*dist2;
        }
    }
    __syncthreads();

    // ---- phase B: softmax per head (unnormalized e; inv folded into epilogue) ----
    {
        const int w = t >> 6, lane = t & 63;
        for (int h = w; h < HH; h += 8) {
            float* row = aL + h*516;
            float m = -1e30f;
            #pragma unroll
            for (int k = 0; k < 8; ++k) m = fmaxf(m, row[lane + 64*k]);
            #pragma unroll
            for (int off = 32; off > 0; off >>= 1) m = fmaxf(m, __shfl_xor(m, off));
            float ssum = 0.f;
            #pragma unroll
            for (int k = 0; k < 8; ++k) {
                float e = __expf(row[lane + 64*k] - m);
                row[lane + 64*k] = e;
                ssum += e;
            }
            #pragma unroll
            for (int off = 32; off > 0; off >>= 1) ssum += __shfl_xor(ssum, off);
            if (lane == 0) sInv[h] = 1.f / ssum;
        }
    }
    __syncthreads();

    // ---- phase C: homogeneous-wave accumulate ----
    // waves 0-5: typ0 (z stream, ping-pong prefetch). waves 6-7: unified V/VP.
    float4 acc0 = {0,0,0,0}, acc1 = {0,0,0,0}, acc2 = {0,0,0,0};
    int rid = -1, seg = 0;

#define FMA8(ZB, AP0, AP1, AP2, JT) do { \
    float4 av0 = *(const float4*)((AP0) + (JT)); \
    float4 av1 = *(const float4*)((AP1) + (JT)); \
    float4 av2 = *(const float4*)((AP2) + (JT)); \
    float4 aw0 = *(const float4*)((AP0) + (JT) + 4); \
    float4 aw1 = *(const float4*)((AP1) + (JT) + 4); \
    float4 aw2 = *(const float4*)((AP2) + (JT) + 4); \
    fma4(acc0, av0.x, ZB[0]); fma4(acc1, av1.x, ZB[0]); fma4(acc2, av2.x, ZB[0]); \
    fma4(acc0, av0.y, ZB[1]); fma4(acc1, av1.y, ZB[1]); fma4(acc2, av2.y, ZB[1]); \
    fma4(acc0, av0.z, ZB[2]); fma4(acc1, av1.z, ZB[2]); fma4(acc2, av2.z, ZB[2]); \
    fma4(acc0, av0.w, ZB[3]); fma4(acc1, av1.w, ZB[3]); fma4(acc2, av2.w, ZB[3]); \
    fma4(acc0, aw0.x, ZB[4]); fma4(acc1, aw1.x, ZB[4]); fma4(acc2, aw2.x, ZB[4]); \
    fma4(acc0, aw0.y, ZB[5]); fma4(acc1, aw1.y, ZB[5]); fma4(acc2, aw2.y, ZB[5]); \
    fma4(acc0, aw0.z, ZB[6]); fma4(acc1, aw1.z, ZB[6]); fma4(acc2, aw2.z, ZB[6]); \
    fma4(acc0, aw0.w, ZB[7]); fma4(acc1, aw1.w, ZB[7]); fma4(acc2, aw2.w, ZB[7]); \
} while (0)

    if (t < 384) {                       // ---- typ0: opair (z from HBM) ----
        seg = t >> 7;
        rid = t & 127;
        const int hg = rid >> 5, zc4 = rid & 31;
        const int j0 = seg*176;
        const int ngrp = (seg == 2) ? 20 : 22;     // groups of 8 j's (even count)
        const float4* Zp = (const float4*)z + (size_t)bi*512*32 + zc4;
        const float* a0p = aL + hg*516;
        const float* a1p = aL + (hg+4)*516;
        const float* a2p = aL + (hg+8)*516;
        float4 zA[8], zB[8];
        #pragma unroll
        for (int e = 0; e < 8; ++e) zA[e] = Zp[(size_t)(j0+e)*32];
        for (int p = 0; p < ngrp; p += 2) {
            const int jt = j0 + p*8;
            #pragma unroll
            for (int e = 0; e < 8; ++e) zB[e] = Zp[(size_t)(jt+8+e)*32];
            FMA8(zA, a0p, a1p, a2p, jt);
            if (p + 2 < ngrp) {
                #pragma unroll
                for (int e = 0; e < 8; ++e) zA[e] = Zp[(size_t)(jt+16+e)*32];
            }
            FMA8(zB, a0p, a1p, a2p, jt + 8);
        }
    } else if (t < 504) {                // ---- unified typ1/typ2 (V / VP from L2) ----
        const int v = t - 384;
        seg = v / 40;
        const int w = v % 40;
        rid = 128 + w;
        const int j0 = seg*176, j1 = (seg == 2) ? 512 : j0 + 176;
        const float4* P; int S, D, O, hg;
        if (w < 16) {
            hg = w >> 2; S = 48; D = 16; O = hg*4 + (w & 3);
            P = (const float4*)(ws + OFF_V) + (size_t)b*512*48;
        } else {
            const int v2 = w - 16;
            hg = v2 / 6; S = 72; D = 24; O = hg*6 + v2 % 6;
            P = (const float4*)(ws + OFF_VP) + (size_t)b*512*72;
        }
        const float* a0p = aL + hg*516;
        const float* a1p = aL + (hg+4)*516;
        const float* a2p = aL + (hg+8)*516;
        #pragma unroll 2
        for (int jt = j0; jt < j1; jt += 4) {
            float4 av0 = *(const float4*)(a0p + jt);
            float4 av1 = *(const float4*)(a1p + jt);
            float4 av2 = *(const float4*)(a2p + jt);
            #pragma unroll
            for (int e = 0; e < 4; ++e) {
                const size_t base = (size_t)(jt+e)*S + O;
                fma4(acc0, ((const float*)&av0)[e], P[base]);
                fma4(acc1, ((const float*)&av1)[e], P[base + D]);
                fma4(acc2, ((const float*)&av2)[e], P[base + 2*D]);
            }
        }
    }
    __syncthreads();                       // all reads of aL done
    float4* sc4 = (float4*)aL;             // reuse aL: [3 seg][168 rid][3 acc] f4
    if (rid >= 0) {
        const int si = (seg*168 + rid)*3;
        sc4[si] = acc0; sc4[si+1] = acc1; sc4[si+2] = acc2;
    }
    __syncthreads();

    if (t < 168) {
        float4 r0 = {0,0,0,0}, r1 = {0,0,0,0}, r2 = {0,0,0,0};
        #pragma unroll
        for (int ss = 0; ss < 3; ++ss) {
            const int si = (ss*168 + t)*3;
            add4(r0, sc4[si]); add4(r1, sc4[si+1]); add4(r2, sc4[si+2]);
        }
        int typ, hg;
        if (t < 128)      { typ = 0; hg = t >> 5; }
        else if (t < 144) { typ = 1; hg = (t-128) >> 2; }
        else              { typ = 2; hg = (t-144) / 6; }
        mul4(r0, sInv[hg]); mul4(r1, sInv[hg+4]); mul4(r2, sInv[hg+8]);
        float4* cat4 = (float4*)(ws + OFF_CAT);
        const size_t cb = (size_t)bi * 528;          // 2112/4
        if (typ == 0) {
            const int zc4 = t & 31;
            cat4[cb + 144 + (hg  )*32 + zc4] = r0;
            cat4[cb + 144 + (hg+4)*32 + zc4] = r1;
            cat4[cb + 144 + (hg+8)*32 + zc4] = r2;
        } else if (typ == 1) {
            const int c4 = (t-128) & 3;
            cat4[cb + (hg  )*4 + c4] = r0;
            cat4[cb + (hg+4)*4 + c4] = r1;
            cat4[cb + (hg+8)*4 + c4] = r2;
        } else {
            const int po = (t-144) % 6;
            optgS4[(hg  )*6 + po] = r0;
            optgS4[(hg+4)*6 + po] = r1;
            optgS4[(hg+8)*6 + po] = r2;
        }
    }
    __syncthreads();

    if (t < 96) {
        const float* og = (const float*)optgS4;
        int h = t >> 3, p = t & 7;
        int o = h*24 + p*3;
        float d0 = og[o]   - tiL[0];
        float d1 = og[o+1] - tiL[1];
        float d2 = og[o+2] - tiL[2];
        float ox = RiL[0]*d0 + RiL[3]*d1 + RiL[6]*d2;
        float oy = RiL[1]*d0 + RiL[4]*d1 + RiL[7]*d2;
        float oz = RiL[2]*d0 + RiL[5]*d1 + RiL[8]*d2;
        float* cat = ws + OFF_CAT + (size_t)bi*CATD;
        cat[192 + o]     = ox;
        cat[192 + o + 1] = oy;
        cat[192 + o + 2] = oz;
        cat[480 + h*8 + p] = sqrtf(ox*ox + oy*oy + oz*oz + 1e-8f);
    }
}

// ---------------- Kernel 4: out = cat @ Wout (cat via scalar loads) ---------
__global__ __launch_bounds__(384) void k_out(
    const float* __restrict__ Wout, const float* __restrict__ ws, float* __restrict__ out)
{
    const int t = threadIdx.x;                 // col 0..383
    const int row0 = blockIdx.x * 4;
    const float* c0 = ws + OFF_CAT + (size_t)(row0+0)*CATD;
    const float* c1 = c0 + CATD;
    const float* c2 = c1 + CATD;
    const float* c3 = c2 + CATD;
    float a0 = 0.f, a1 = 0.f, a2 = 0.f, a3 = 0.f;
    #pragma unroll 8
    for (int r = 0; r < CATD; ++r) {
        float w = Wout[(size_t)r*384 + t];
        a0 += c0[r]*w; a1 += c1[r]*w; a2 += c2[r]*w; a3 += c3[r]*w;
    }
    out[(size_t)(row0+0)*384 + t] = a0;
    out[(size_t)(row0+1)*384 + t] = a1;
    out[(size_t)(row0+2)*384 + t] = a2;
    out[(size_t)(row0+3)*384 + t] = a3;
}

extern "C" void kernel_launch(void* const* d_in, const int* in_sizes, int n_in,
                              void* d_out, int out_size, void* d_ws, size_t ws_size,
                              hipStream_t stream)
{
    const float* s    = (const float*)d_in[0];
    const float* z    = (const float*)d_in[1];
    const float* R    = (const float*)d_in[2];
    const float* tt   = (const float*)d_in[3];
    const float* Wq   = (const float*)d_in[4];
    const float* Wk   = (const float*)d_in[5];
    const float* Wv   = (const float*)d_in[6];
    const float* Wqp  = (const float*)d_in[7];
    const float* Wkp  = (const float*)d_in[8];
    const float* Wvp  = (const float*)d_in[9];
    const float* Wb   = (const float*)d_in[10];
    const float* hw   = (const float*)d_in[11];
    const float* Wout = (const float*)d_in[12];
    float* ws  = (float*)d_ws;
    float* out = (float*)d_out;

    hipLaunchKernelGGL(k_proj, dim3(BN/2),     dim3(256), 0, stream,
                       s, R, tt, Wq, Wk, Wv, Wqp, Wkp, Wvp, ws);
    hipLaunchKernelGGL(k_bias, dim3(BN*NN/64), dim3(256), 0, stream, z, Wb, ws);
    hipLaunchKernelGGL(k_attn, dim3(BN),       dim3(512), 0, stream, z, R, tt, hw, ws);
    hipLaunchKernelGGL(k_out,  dim3(BN/4),     dim3(384), 0, stream, Wout, ws, out);
}

// Round 5
// 739.872 us; speedup vs baseline: 2.1720x; 1.0858x over previous
//
#include <hip/hip_runtime.h>
#include <math.h>

#define BB 2
#define NN 512
#define SDIM 384
#define ZDIM 128
#define HH 12
#define CDIM 16
#define PQ 4
#define PV 8
#define BN (BB*NN)        // 1024
#define CATD 2112

#define WL  0.57735026918962576f
#define LAM 0.06804138174397717f   // wL*wC/2, wC = sqrt(2/(9*PQ))

// ---- workspace layout (float offsets) ----
#define OFF_Q    0                         // [1024][192] rows
#define OFF_QP   196608                    // [1024][144] rows
#define OFF_QQ   344064                    // [1024][12]
#define OFF_KT4  356352                    // f4: [2][48][512]  (c4-group major, n minor)
#define OFF_KPT4 552960                    // f4: [2][36][512]
#define OFF_KKT  700416                    // [2][12][512]
#define OFF_V    712704                    // [1024][192] rows (f4 view [1024][48])
#define OFF_VP   909312                    // [1024][288] rows (f4 view [1024][72])
#define OFF_CAT  7495680                   // [1024][2112]

__device__ __forceinline__ float dot4(float4 a, float4 b) {
    return a.x*b.x + a.y*b.y + a.z*b.z + a.w*b.w;
}
__device__ __forceinline__ void fma4(float4& a, float s, float4 b) {
    a.x += s*b.x; a.y += s*b.y; a.z += s*b.z; a.w += s*b.w;
}
__device__ __forceinline__ void add4(float4& a, float4 b) {
    a.x += b.x; a.y += b.y; a.z += b.z; a.w += b.w;
}
__device__ __forceinline__ void mul4(float4& a, float s) {
    a.x *= s; a.y *= s; a.z *= s; a.w *= s;
}

// ---------------- Kernel 1: projections + frame transform -------------------
// 2 rows per block, 512 blocks. s rows read via scalar loads (uniform).
__global__ __launch_bounds__(256) void k_proj(
    const float* __restrict__ s, const float* __restrict__ Rg, const float* __restrict__ tg,
    const float* __restrict__ Wq, const float* __restrict__ Wk, const float* __restrict__ Wv,
    const float* __restrict__ Wqp, const float* __restrict__ Wkp, const float* __restrict__ Wvp,
    float* __restrict__ ws)
{
    __shared__ float4 pL4[2][144];   // point projections (local frame), rows 0/1
    __shared__ float  sqL[2][96];    // |qp|^2 [0:48), |kp|^2 [48:96)
    __shared__ float  Rt[2][12];
    const int t = threadIdx.x;
    const int n0 = blockIdx.x * 2;
    const int b  = n0 >> 9;
    const int nloc = n0 & 511;

    if (t < 24) {
        int rr = t / 12, c = t % 12;
        Rt[rr][c] = (c < 9) ? Rg[(n0+rr)*9 + c] : tg[(n0+rr)*3 + (c-9)];
    }
    const float* s0 = s + (size_t)n0*SDIM;
    const float* s1 = s0 + SDIM;
    __syncthreads();

    float4* Q4g  = (float4*)(ws + OFF_Q);
    float4* V4g  = (float4*)(ws + OFF_V);
    float4* KT4g = (float4*)(ws + OFF_KT4);

    for (int it = 0; it < 2; ++it) {
        int g = t + it*256;
        if (g >= 288) break;
        const float4* W4; int wc4, ld4, dst;
        if (g < 48)       { W4 = (const float4*)Wq;  wc4 = g;     ld4 = 48; dst = 0; }
        else if (g < 96)  { W4 = (const float4*)Wk;  wc4 = g-48;  ld4 = 48; dst = 1; }
        else if (g < 144) { W4 = (const float4*)Wv;  wc4 = g-96;  ld4 = 48; dst = 2; }
        else if (g < 180) { W4 = (const float4*)Wqp; wc4 = g-144; ld4 = 36; dst = 3; }
        else if (g < 216) { W4 = (const float4*)Wkp; wc4 = g-180; ld4 = 36; dst = 4; }
        else              { W4 = (const float4*)Wvp; wc4 = g-216; ld4 = 72; dst = 5; }
        float4 acc0 = {0,0,0,0}, acc1 = {0,0,0,0};
        #pragma unroll 4
        for (int r = 0; r < SDIM; ++r) {
            float4 wv = W4[r*ld4 + wc4];
            float f0 = s0[r], f1 = s1[r];
            fma4(acc0, f0, wv);
            fma4(acc1, f1, wv);
        }
        if (dst == 0) {
            Q4g[(size_t)n0*48 + wc4] = acc0;
            Q4g[(size_t)(n0+1)*48 + wc4] = acc1;
        } else if (dst == 1) {
            size_t base = ((size_t)(b*48 + wc4))*512 + nloc;
            KT4g[base] = acc0; KT4g[base+1] = acc1;
        } else if (dst == 2) {
            V4g[(size_t)n0*48 + wc4] = acc0;
            V4g[(size_t)(n0+1)*48 + wc4] = acc1;
        } else if (dst == 3) {
            pL4[0][wc4] = acc0; pL4[1][wc4] = acc1;
        } else if (dst == 4) {
            pL4[0][36+wc4] = acc0; pL4[1][36+wc4] = acc1;
        } else {
            pL4[0][72+wc4] = acc0; pL4[1][72+wc4] = acc1;
        }
    }
    __syncthreads();

    // local -> global frame
    for (int task = t; task < 384; task += 256) {
        int rr = task / 192, pt = task % 192;
        const float* pl = (const float*)pL4[rr];
        int off = (pt < 48) ? pt*3 : (pt < 96 ? 144 + (pt-48)*3 : 288 + (pt-96)*3);
        float p0 = pl[off], p1 = pl[off+1], p2 = pl[off+2];
        const float* R = Rt[rr];
        float g0 = R[0]*p0 + R[1]*p1 + R[2]*p2 + R[9];
        float g1 = R[3]*p0 + R[4]*p1 + R[5]*p2 + R[10];
        float g2 = R[6]*p0 + R[7]*p1 + R[8]*p2 + R[11];
        int bn = n0 + rr, n = bn & 511;
        if (pt < 48) {
            int o = pt*3;
            float* d = ws + OFF_QP + (size_t)bn*144 + o;
            d[0] = g0; d[1] = g1; d[2] = g2;
            sqL[rr][pt] = g0*g0 + g1*g1 + g2*g2;
        } else if (pt < 96) {
            int pc = (pt-48)*3;
            float gg[3] = {g0,g1,g2};
            #pragma unroll
            for (int x = 0; x < 3; ++x) {
                int pcx = pc + x;
                ws[OFF_KPT4 + (((size_t)(b*36 + (pcx>>2)))*512 + n)*4 + (pcx&3)] = gg[x];
            }
            sqL[rr][pt] = g0*g0 + g1*g1 + g2*g2;
        } else {
            int o = (pt-96)*3;
            float* d = ws + OFF_VP + (size_t)bn*288 + o;
            d[0] = g0; d[1] = g1; d[2] = g2;
        }
    }
    __syncthreads();

    if (t < 48) {
        int rr = t / 24, u = t % 24;
        int bn = n0 + rr, n = bn & 511;
        if (u < 12) {
            float sm = sqL[rr][u*4] + sqL[rr][u*4+1] + sqL[rr][u*4+2] + sqL[rr][u*4+3];
            ws[OFF_QQ + (size_t)bn*12 + u] = sm;
        } else {
            int h = u - 12;
            float sm = sqL[rr][48+h*4] + sqL[rr][48+h*4+1] + sqL[rr][48+h*4+2] + sqL[rr][48+h*4+3];
            ws[OFF_KKT + ((size_t)(b*12 + h))*512 + n] = sm;
        }
    }
}

// ---------------- Kernel 2: fused attention per (b,i) -----------------------
// Pair bias computed INLINE in phase A (z row per thread, Wb via s_loads) —
// k_bias kernel eliminated. Phase C: homogeneous waves + ping-pong z prefetch.
__global__ __launch_bounds__(512, 2) void k_attn(
    const float* __restrict__ z, const float* __restrict__ Rg, const float* __restrict__ tg,
    const float* __restrict__ hw, const float* __restrict__ Wb, float* __restrict__ ws)
{
    __shared__ __align__(16) float aL[HH*516];   // logits/probs; reused as reduce scratch
    __shared__ float4 optgS4[72];
    __shared__ float RiL[9], tiL[3], sInv[12];

    const int t = threadIdx.x;
    // batch-aware XCD swizzle: XCDs 0..3 get batch 0, 4..7 batch 1 (perf only)
    const int d = blockIdx.x;
    const int xcd = d & 7, slot = d >> 3;
    const int bi = (xcd < 4) ? (xcd*128 + slot) : (512 + (xcd-4)*128 + slot);
    const int b = bi >> 9;

    if (t < 9)             RiL[t]   = Rg[bi*9 + t];
    if (t >= 9 && t < 12)  tiL[t-9] = tg[bi*3 + (t-9)];

    // gamma (uniform, per-thread registers)
    float gam[HH];
    #pragma unroll
    for (int h = 0; h < HH; ++h) {
        float x = hw[h];
        gam[h] = (x > 20.f) ? x : log1pf(__expf(x));
    }

    // ---- phase A: inline pair bias + logits, thread <-> j ----
    {
        const int j = t;
        // bias: pb[h] = sum_c z[bi,j,c] * Wb[c,h]   (z row f4 loads; Wb -> s_load)
        float pb[HH];
        #pragma unroll
        for (int h = 0; h < HH; ++h) pb[h] = 0.f;
        const float4* zrow4 = (const float4*)z + ((size_t)bi*512 + j)*32;
        #pragma unroll 4
        for (int c4 = 0; c4 < 32; ++c4) {
            const float4 zq = zrow4[c4];
            const float* wb = Wb + c4*48;          // uniform across threads
            #pragma unroll
            for (int e = 0; e < 4; ++e) {
                const float zv = ((const float*)&zq)[e];
                const float* w = wb + e*12;
                #pragma unroll
                for (int h = 0; h < HH; ++h) pb[h] += zv * w[h];
            }
        }
        const float4* Q4u  = (const float4*)(ws + OFF_Q  + (size_t)bi*192);
        const float4* QP4u = (const float4*)(ws + OFF_QP + (size_t)bi*144);
        const float*  QQu  = ws + OFF_QQ + (size_t)bi*12;
        const float4* KT4  = (const float4*)(ws + OFF_KT4)  + (size_t)b*48*512;
        const float4* KPT4 = (const float4*)(ws + OFF_KPT4) + (size_t)b*36*512;
        const float*  KKT  = ws + OFF_KKT  + (size_t)b*12*512;
        for (int h = 0; h < HH; ++h) {
            float scal = 0.f, qk = 0.f;
            #pragma unroll
            for (int cg = 0; cg < 4; ++cg)
                scal += dot4(Q4u[h*4+cg], KT4[(h*4+cg)*512 + j]);
            #pragma unroll
            for (int pg = 0; pg < 3; ++pg)
                qk += dot4(QP4u[h*3+pg], KPT4[(h*3+pg)*512 + j]);
            float dist2 = QQu[h] + KKT[h*512 + j] - 2.f*qk;
            aL[h*516 + j] = WL*(scal*0.25f + pb[h]) - LAM*gam[h]*dist2;
        }
    }
    __syncthreads();

    // ---- phase B: softmax per head (unnormalized e; inv folded into epilogue) ----
    {
        const int w = t >> 6, lane = t & 63;
        for (int h = w; h < HH; h += 8) {
            float* row = aL + h*516;
            float m = -1e30f;
            #pragma unroll
            for (int k = 0; k < 8; ++k) m = fmaxf(m, row[lane + 64*k]);
            #pragma unroll
            for (int off = 32; off > 0; off >>= 1) m = fmaxf(m, __shfl_xor(m, off));
            float ssum = 0.f;
            #pragma unroll
            for (int k = 0; k < 8; ++k) {
                float e = __expf(row[lane + 64*k] - m);
                row[lane + 64*k] = e;
                ssum += e;
            }
            #pragma unroll
            for (int off = 32; off > 0; off >>= 1) ssum += __shfl_xor(ssum, off);
            if (lane == 0) sInv[h] = 1.f / ssum;
        }
    }
    __syncthreads();

    // ---- phase C: homogeneous-wave accumulate ----
    // waves 0-5: typ0 (z stream, ping-pong prefetch). waves 6-7: unified V/VP.
    float4 acc0 = {0,0,0,0}, acc1 = {0,0,0,0}, acc2 = {0,0,0,0};
    int rid = -1, seg = 0;

#define FMA8(ZB, AP0, AP1, AP2, JT) do { \
    float4 av0 = *(const float4*)((AP0) + (JT)); \
    float4 av1 = *(const float4*)((AP1) + (JT)); \
    float4 av2 = *(const float4*)((AP2) + (JT)); \
    float4 aw0 = *(const float4*)((AP0) + (JT) + 4); \
    float4 aw1 = *(const float4*)((AP1) + (JT) + 4); \
    float4 aw2 = *(const float4*)((AP2) + (JT) + 4); \
    fma4(acc0, av0.x, ZB[0]); fma4(acc1, av1.x, ZB[0]); fma4(acc2, av2.x, ZB[0]); \
    fma4(acc0, av0.y, ZB[1]); fma4(acc1, av1.y, ZB[1]); fma4(acc2, av2.y, ZB[1]); \
    fma4(acc0, av0.z, ZB[2]); fma4(acc1, av1.z, ZB[2]); fma4(acc2, av2.z, ZB[2]); \
    fma4(acc0, av0.w, ZB[3]); fma4(acc1, av1.w, ZB[3]); fma4(acc2, av2.w, ZB[3]); \
    fma4(acc0, aw0.x, ZB[4]); fma4(acc1, aw1.x, ZB[4]); fma4(acc2, aw2.x, ZB[4]); \
    fma4(acc0, aw0.y, ZB[5]); fma4(acc1, aw1.y, ZB[5]); fma4(acc2, aw2.y, ZB[5]); \
    fma4(acc0, aw0.z, ZB[6]); fma4(acc1, aw1.z, ZB[6]); fma4(acc2, aw2.z, ZB[6]); \
    fma4(acc0, aw0.w, ZB[7]); fma4(acc1, aw1.w, ZB[7]); fma4(acc2, aw2.w, ZB[7]); \
} while (0)

    if (t < 384) {                       // ---- typ0: opair (z, L2-hot after phase A) ----
        seg = t >> 7;
        rid = t & 127;
        const int hg = rid >> 5, zc4 = rid & 31;
        const int j0 = seg*176;
        const int ngrp = (seg == 2) ? 20 : 22;     // groups of 8 j's (even count)
        const float4* Zp = (const float4*)z + (size_t)bi*512*32 + zc4;
        const float* a0p = aL + hg*516;
        const float* a1p = aL + (hg+4)*516;
        const float* a2p = aL + (hg+8)*516;
        float4 zA[8], zB[8];
        #pragma unroll
        for (int e = 0; e < 8; ++e) zA[e] = Zp[(size_t)(j0+e)*32];
        for (int p = 0; p < ngrp; p += 2) {
            const int jt = j0 + p*8;
            #pragma unroll
            for (int e = 0; e < 8; ++e) zB[e] = Zp[(size_t)(jt+8+e)*32];
            FMA8(zA, a0p, a1p, a2p, jt);
            if (p + 2 < ngrp) {
                #pragma unroll
                for (int e = 0; e < 8; ++e) zA[e] = Zp[(size_t)(jt+16+e)*32];
            }
            FMA8(zB, a0p, a1p, a2p, jt + 8);
        }
    } else if (t < 504) {                // ---- unified typ1/typ2 (V / VP from L2) ----
        const int v = t - 384;
        seg = v / 40;
        const int w = v % 40;
        rid = 128 + w;
        const int j0 = seg*176, j1 = (seg == 2) ? 512 : j0 + 176;
        const float4* P; int S, D, O, hg;
        if (w < 16) {
            hg = w >> 2; S = 48; D = 16; O = hg*4 + (w & 3);
            P = (const float4*)(ws + OFF_V) + (size_t)b*512*48;
        } else {
            const int v2 = w - 16;
            hg = v2 / 6; S = 72; D = 24; O = hg*6 + v2 % 6;
            P = (const float4*)(ws + OFF_VP) + (size_t)b*512*72;
        }
        const float* a0p = aL + hg*516;
        const float* a1p = aL + (hg+4)*516;
        const float* a2p = aL + (hg+8)*516;
        #pragma unroll 2
        for (int jt = j0; jt < j1; jt += 4) {
            float4 av0 = *(const float4*)(a0p + jt);
            float4 av1 = *(const float4*)(a1p + jt);
            float4 av2 = *(const float4*)(a2p + jt);
            #pragma unroll
            for (int e = 0; e < 4; ++e) {
                const size_t base = (size_t)(jt+e)*S + O;
                fma4(acc0, ((const float*)&av0)[e], P[base]);
                fma4(acc1, ((const float*)&av1)[e], P[base + D]);
                fma4(acc2, ((const float*)&av2)[e], P[base + 2*D]);
            }
        }
    }
    __syncthreads();                       // all reads of aL done
    float4* sc4 = (float4*)aL;             // reuse aL: [3 seg][168 rid][3 acc] f4
    if (rid >= 0) {
        const int si = (seg*168 + rid)*3;
        sc4[si] = acc0; sc4[si+1] = acc1; sc4[si+2] = acc2;
    }
    __syncthreads();

    if (t < 168) {
        float4 r0 = {0,0,0,0}, r1 = {0,0,0,0}, r2 = {0,0,0,0};
        #pragma unroll
        for (int ss = 0; ss < 3; ++ss) {
            const int si = (ss*168 + t)*3;
            add4(r0, sc4[si]); add4(r1, sc4[si+1]); add4(r2, sc4[si+2]);
        }
        int typ, hg;
        if (t < 128)      { typ = 0; hg = t >> 5; }
        else if (t < 144) { typ = 1; hg = (t-128) >> 2; }
        else              { typ = 2; hg = (t-144) / 6; }
        mul4(r0, sInv[hg]); mul4(r1, sInv[hg+4]); mul4(r2, sInv[hg+8]);
        float4* cat4 = (float4*)(ws + OFF_CAT);
        const size_t cb = (size_t)bi * 528;          // 2112/4
        if (typ == 0) {
            const int zc4 = t & 31;
            cat4[cb + 144 + (hg  )*32 + zc4] = r0;
            cat4[cb + 144 + (hg+4)*32 + zc4] = r1;
            cat4[cb + 144 + (hg+8)*32 + zc4] = r2;
        } else if (typ == 1) {
            const int c4 = (t-128) & 3;
            cat4[cb + (hg  )*4 + c4] = r0;
            cat4[cb + (hg+4)*4 + c4] = r1;
            cat4[cb + (hg+8)*4 + c4] = r2;
        } else {
            const int po = (t-144) % 6;
            optgS4[(hg  )*6 + po] = r0;
            optgS4[(hg+4)*6 + po] = r1;
            optgS4[(hg+8)*6 + po] = r2;
        }
    }
    __syncthreads();

    if (t < 96) {
        const float* og = (const float*)optgS4;
        int h = t >> 3, p = t & 7;
        int o = h*24 + p*3;
        float d0 = og[o]   - tiL[0];
        float d1 = og[o+1] - tiL[1];
        float d2 = og[o+2] - tiL[2];
        float ox = RiL[0]*d0 + RiL[3]*d1 + RiL[6]*d2;
        float oy = RiL[1]*d0 + RiL[4]*d1 + RiL[7]*d2;
        float oz = RiL[2]*d0 + RiL[5]*d1 + RiL[8]*d2;
        float* cat = ws + OFF_CAT + (size_t)bi*CATD;
        cat[192 + o]     = ox;
        cat[192 + o + 1] = oy;
        cat[192 + o + 2] = oz;
        cat[480 + h*8 + p] = sqrtf(ox*ox + oy*oy + oz*oz + 1e-8f);
    }
}

// ---------------- Kernel 3: out = cat @ Wout (cat via scalar loads) ---------
__global__ __launch_bounds__(384) void k_out(
    const float* __restrict__ Wout, const float* __restrict__ ws, float* __restrict__ out)
{
    const int t = threadIdx.x;                 // col 0..383
    const int row0 = blockIdx.x * 4;
    const float* c0 = ws + OFF_CAT + (size_t)(row0+0)*CATD;
    const float* c1 = c0 + CATD;
    const float* c2 = c1 + CATD;
    const float* c3 = c2 + CATD;
    float a0 = 0.f, a1 = 0.f, a2 = 0.f, a3 = 0.f;
    #pragma unroll 8
    for (int r = 0; r < CATD; ++r) {
        float w = Wout[(size_t)r*384 + t];
        a0 += c0[r]*w; a1 += c1[r]*w; a2 += c2[r]*w; a3 += c3[r]*w;
    }
    out[(size_t)(row0+0)*384 + t] = a0;
    out[(size_t)(row0+1)*384 + t] = a1;
    out[(size_t)(row0+2)*384 + t] = a2;
    out[(size_t)(row0+3)*384 + t] = a3;
}

extern "C" void kernel_launch(void* const* d_in, const int* in_sizes, int n_in,
                              void* d_out, int out_size, void* d_ws, size_t ws_size,
                              hipStream_t stream)
{
    const float* s    = (const float*)d_in[0];
    const float* z    = (const float*)d_in[1];
    const float* R    = (const float*)d_in[2];
    const float* tt   = (const float*)d_in[3];
    const float* Wq   = (const float*)d_in[4];
    const float* Wk   = (const float*)d_in[5];
    const float* Wv   = (const float*)d_in[6];
    const float* Wqp  = (const float*)d_in[7];
    const float* Wkp  = (const float*)d_in[8];
    const float* Wvp  = (const float*)d_in[9];
    const float* Wb   = (const float*)d_in[10];
    const float* hw   = (const float*)d_in[11];
    const float* Wout = (const float*)d_in[12];
    float* ws  = (float*)d_ws;
    float* out = (float*)d_out;

    hipLaunchKernelGGL(k_proj, dim3(BN/2), dim3(256), 0, stream,
                       s, R, tt, Wq, Wk, Wv, Wqp, Wkp, Wvp, ws);
    hipLaunchKernelGGL(k_attn, dim3(BN),   dim3(512), 0, stream, z, R, tt, hw, Wb, ws);
    hipLaunchKernelGGL(k_out,  dim3(BN/4), dim3(384), 0, stream, Wout, ws, out);
}